// Round 1
// baseline (279.456 us; speedup 1.0000x reference)
//
#include <hip/hip_runtime.h>
#include <math.h>

// AR-GAS Student-t score-driven filter, K = 4194304 sequential steps.
// Parallelization: chunked scan with burn-in. The recurrence is contractive
// (per-step Jacobian norm ~0.93 avg, <=0.99 worst), so a thread starting from
// the stationary guess (mu=0, s2=omega_s/(1-beta_s)=1) B steps before its
// chunk converges to the true trajectory to ~e^-50 (B=1024) before it starts
// emitting. Chunk 0 starts from the exact provided initial state.
//
// Per step (algebraically == reference):
//   r     = y - mu
//   scale = (nu+1)*s2 / (nu*s2 + r^2)          // == (1+1/nu)/(1+r^2/(nu*s2))
//   mu'   = w_mu + b_mu*(mu + a_mu*scale*r)
//   s2'   = w_s  + b_s *(s2 + a_s*(scale*r^2 - s2))
// Outputs: out[0..K)   = mu'
//          out[K..2K)  = sqrt(s2')

#define CHUNK 64
#define BURN  1024

__global__ __launch_bounds__(256, 1)
void ar_gas_kernel(const float* __restrict__ y,
                   const float* __restrict__ p_last_mu,
                   const float* __restrict__ p_last_s2,
                   const float* __restrict__ p_amu,
                   const float* __restrict__ p_as,
                   const float* __restrict__ p_bmu,
                   const float* __restrict__ p_bs,
                   const float* __restrict__ p_wmu,
                   const float* __restrict__ p_ws,
                   const float* __restrict__ p_nu,
                   const float* __restrict__ p_str,
                   float* __restrict__ out,
                   int n)
{
    const int tid = blockIdx.x * blockDim.x + threadIdx.x;
    const long start = (long)tid * CHUNK;
    if (start >= n) return;

    const float nu       = *p_nu;
    const float strength = *p_str;
    const float a_mu = (*p_amu) * strength;
    const float a_s  = (*p_as)  * strength;
    const float b_mu = *p_bmu;
    const float b_s  = *p_bs;
    const float w_mu = *p_wmu;
    const float w_s  = *p_ws;

    const float c1  = nu + 1.0f;            // scale numerator coeff
    const float bam = b_mu * a_mu;          // mu' = bam*sr + (b_mu*mu + w_mu)
    const float bas = b_s * a_s;            // s2' = bas*sr*r + (c3*s2 + w_s)
    const float c3  = b_s * (1.0f - a_s);

    float mu, s2;
    long i0 = start - (long)BURN;
    if (i0 < 0) {
        i0 = 0;
        mu = *p_last_mu;
        s2 = *p_last_s2;     // "last_sigma" is treated as variance
    } else {
        mu = 0.0f;           // stationary-point guess; burn-in erases it
        s2 = 1.0f;           // w_s/(1-b_s) = 0.02/0.02 = 1
    }

    // ---- burn-in: converge onto the true trajectory ----
    for (long i = i0; i < start; ++i) {
        float yv  = y[i];
        float r   = yv - mu;
        float den = fmaf(r, r, nu * s2);
        float inv = __builtin_amdgcn_rcpf(den);
        float sr  = (c1 * s2) * inv * r;              // scale * r
        float mu_n = fmaf(bam, sr, fmaf(b_mu, mu, w_mu));
        float s2_n = fmaf(bas, sr * r, fmaf(c3, s2, w_s));
        mu = mu_n;
        s2 = s2_n;
    }

    // ---- emit this chunk ----
    float* __restrict__ out_mu = out;
    float* __restrict__ out_sg = out + n;
    const long end = start + CHUNK;
    for (long i = start; i < end; ++i) {
        float yv  = y[i];
        float r   = yv - mu;
        float den = fmaf(r, r, nu * s2);
        float inv = __builtin_amdgcn_rcpf(den);
        float sr  = (c1 * s2) * inv * r;
        mu = fmaf(bam, sr, fmaf(b_mu, mu, w_mu));
        s2 = fmaf(bas, sr * r, fmaf(c3, s2, w_s));
        out_mu[i] = mu;
        out_sg[i] = __builtin_amdgcn_sqrtf(s2);
    }
}

extern "C" void kernel_launch(void* const* d_in, const int* in_sizes, int n_in,
                              void* d_out, int out_size, void* d_ws, size_t ws_size,
                              hipStream_t stream) {
    const float* y    = (const float*)d_in[0];
    const int n       = in_sizes[0];          // 4194304
    const int threads = (n + CHUNK - 1) / CHUNK;   // 65536
    const int block   = 256;
    const int grid    = (threads + block - 1) / block;  // 256 blocks -> 1/CU

    ar_gas_kernel<<<grid, block, 0, stream>>>(
        y,
        (const float*)d_in[1],  // last_mu
        (const float*)d_in[2],  // last_sigma (variance)
        (const float*)d_in[3],  // alpha_mu
        (const float*)d_in[4],  // alpha_sigma
        (const float*)d_in[5],  // beta_mu
        (const float*)d_in[6],  // beta_sigma
        (const float*)d_in[7],  // omega_mu
        (const float*)d_in[8],  // omega_sigma
        (const float*)d_in[9],  // nu
        (const float*)d_in[10], // norm_strength
        (float*)d_out, n);
}

// Round 2
// 168.026 us; speedup vs baseline: 1.6632x; 1.6632x over previous
//
#include <hip/hip_runtime.h>
#include <math.h>

// AR-GAS Student-t score-driven filter, K = 4194304 sequential steps.
// Chunked scan with burn-in (contractive recurrence, per-step Jacobian ~0.94).
// R2: float4 double-buffered prefetch (loads off the serial chain), int
// indexing, float4 stores, CHUNK 64->32 + BURN 1024->512 (2 waves/SIMD).

#define CHUNK 32
#define BURN  512

__device__ __forceinline__ void gas_step(float yv, float& mu, float& s2,
                                         float nu, float c1, float bam,
                                         float bas, float c3, float b_mu,
                                         float w_mu, float w_s)
{
    float r   = yv - mu;
    float den = fmaf(r, r, nu * s2);            // nu*s2 off-chain (parallel with r)
    float inv = __builtin_amdgcn_rcpf(den);
    float sr  = (c1 * s2) * inv * r;            // scale * r
    float m2  = fmaf(b_mu, mu, w_mu);           // off-chain
    float s2b = fmaf(c3, s2, w_s);              // off-chain
    mu = fmaf(bam, sr, m2);
    s2 = fmaf(bas, sr * r, s2b);
}

__global__ __launch_bounds__(256, 2)
void ar_gas_kernel(const float* __restrict__ y,
                   const float* __restrict__ p_last_mu,
                   const float* __restrict__ p_last_s2,
                   const float* __restrict__ p_amu,
                   const float* __restrict__ p_as,
                   const float* __restrict__ p_bmu,
                   const float* __restrict__ p_bs,
                   const float* __restrict__ p_wmu,
                   const float* __restrict__ p_ws,
                   const float* __restrict__ p_nu,
                   const float* __restrict__ p_str,
                   float* __restrict__ out,
                   int n)
{
    const int tid   = blockIdx.x * blockDim.x + threadIdx.x;
    const int start = tid * CHUNK;
    if (start >= n) return;

    const float nu       = *p_nu;
    const float strength = *p_str;
    const float a_mu = (*p_amu) * strength;
    const float a_s  = (*p_as)  * strength;
    const float b_mu = *p_bmu;
    const float b_s  = *p_bs;
    const float w_mu = *p_wmu;
    const float w_s  = *p_ws;

    const float c1  = nu + 1.0f;
    const float bam = b_mu * a_mu;
    const float bas = b_s * a_s;
    const float c3  = b_s * (1.0f - a_s);

    float mu, s2;
    int i0 = start - BURN;
    if (i0 < 0) {
        i0 = 0;
        mu = *p_last_mu;
        s2 = *p_last_s2;       // "last_sigma" is the variance
    } else {
        mu = 0.0f;             // stationary guess; burn-in erases it
        s2 = 1.0f;             // w_s/(1-b_s) = 1
    }

    // ---- burn-in: double-buffered float4 prefetch; i0, start are x4-aligned
    int i = i0;
    float4 cur = *(const float4*)(y + i);
    while (i < start) {
        int ip = i + 4;                        // ip <= start < n: always valid
        float4 nxt = *(const float4*)(y + ip);
        gas_step(cur.x, mu, s2, nu, c1, bam, bas, c3, b_mu, w_mu, w_s);
        gas_step(cur.y, mu, s2, nu, c1, bam, bas, c3, b_mu, w_mu, w_s);
        gas_step(cur.z, mu, s2, nu, c1, bam, bas, c3, b_mu, w_mu, w_s);
        gas_step(cur.w, mu, s2, nu, c1, bam, bas, c3, b_mu, w_mu, w_s);
        cur = nxt;
        i = ip;
    }

    // ---- emit: 4 steps per float4, vector stores
    float4* __restrict__ out_mu = (float4*)(out + start);
    float4* __restrict__ out_sg = (float4*)(out + n + start);
    #pragma unroll
    for (int j = 0; j < CHUNK / 4; ++j) {
        int ip  = i + 4;
        int ipc = (ip <= n - 4) ? ip : i;      // clamp last prefetch (OOB guard)
        float4 nxt = *(const float4*)(y + ipc);

        float4 m4, g4;
        gas_step(cur.x, mu, s2, nu, c1, bam, bas, c3, b_mu, w_mu, w_s);
        m4.x = mu; g4.x = __builtin_amdgcn_sqrtf(s2);
        gas_step(cur.y, mu, s2, nu, c1, bam, bas, c3, b_mu, w_mu, w_s);
        m4.y = mu; g4.y = __builtin_amdgcn_sqrtf(s2);
        gas_step(cur.z, mu, s2, nu, c1, bam, bas, c3, b_mu, w_mu, w_s);
        m4.z = mu; g4.z = __builtin_amdgcn_sqrtf(s2);
        gas_step(cur.w, mu, s2, nu, c1, bam, bas, c3, b_mu, w_mu, w_s);
        m4.w = mu; g4.w = __builtin_amdgcn_sqrtf(s2);

        out_mu[j] = m4;
        out_sg[j] = g4;
        cur = nxt;
        i = ip;
    }
}

extern "C" void kernel_launch(void* const* d_in, const int* in_sizes, int n_in,
                              void* d_out, int out_size, void* d_ws, size_t ws_size,
                              hipStream_t stream) {
    const float* y    = (const float*)d_in[0];
    const int n       = in_sizes[0];                 // 4194304
    const int threads = (n + CHUNK - 1) / CHUNK;     // 131072
    const int block   = 256;
    const int grid    = (threads + block - 1) / block;  // 512 blocks

    ar_gas_kernel<<<grid, block, 0, stream>>>(
        y,
        (const float*)d_in[1],  // last_mu
        (const float*)d_in[2],  // last_sigma (variance)
        (const float*)d_in[3],  // alpha_mu
        (const float*)d_in[4],  // alpha_sigma
        (const float*)d_in[5],  // beta_mu
        (const float*)d_in[6],  // beta_sigma
        (const float*)d_in[7],  // omega_mu
        (const float*)d_in[8],  // omega_sigma
        (const float*)d_in[9],  // nu
        (const float*)d_in[10], // norm_strength
        (float*)d_out, n);
}

// Round 3
// 114.821 us; speedup vs baseline: 2.4339x; 1.4634x over previous
//
#include <hip/hip_runtime.h>
#include <math.h>

// AR-GAS Student-t filter, K = 4194304 sequential steps.
// Chunked scan with burn-in (contractive map, per-step Jacobian ~0.94).
// R3: per-block LDS staging of y (coalesced float4 global loads, +1/64
// swizzle -> 2-way-free LDS banks), 4-deep register prefetch from LDS,
// outputs transposed through LDS for fully coalesced float4 stores.
// CHUNK 64 (9x work/output), BURN 512 (contraction e^-32), block 128,
// 512 blocks = 2 blocks/CU, ~68 KB LDS/block.

#define CHUNK  64
#define BURN   512
#define BLOCK  128
#define OUTW   (BLOCK * CHUNK)            // 8192 outputs per block
#define REGION (OUTW + BURN)              // 8704 staged y elements
#define SY_SZ  (REGION + 8 + ((REGION + 8) >> 6) + 4)   // 8852 floats
#define SM_SZ  (OUTW + (OUTW >> 6))                     // 8320 floats

__device__ __forceinline__ int SWZ(int e) { return e + (e >> 6); }

__global__ __launch_bounds__(BLOCK, 2)
void ar_gas_kernel(const float* __restrict__ y,
                   const float* __restrict__ p_last_mu,
                   const float* __restrict__ p_last_s2,
                   const float* __restrict__ p_amu,
                   const float* __restrict__ p_as,
                   const float* __restrict__ p_bmu,
                   const float* __restrict__ p_bs,
                   const float* __restrict__ p_wmu,
                   const float* __restrict__ p_ws,
                   const float* __restrict__ p_nu,
                   const float* __restrict__ p_str,
                   float* __restrict__ out,
                   int n)
{
    const int t   = threadIdx.x;
    const int blk = blockIdx.x;
    const int gbase = blk * OUTW - BURN;      // global idx of LDS region elem 0

    __shared__ float sy[SY_SZ];               // staged y; later reused for sigma
    __shared__ float sm[SM_SZ];               // mu staging

    const float nu       = *p_nu;
    const float strength = *p_str;
    const float a_mu = (*p_amu) * strength;
    const float a_s  = (*p_as)  * strength;
    const float b_mu = *p_bmu;
    const float b_s  = *p_bs;
    const float w_mu = *p_wmu;
    const float w_s  = *p_ws;

    const float c1  = nu + 1.0f;              // scale = c1*s2 / (nu*s2 + r^2)
    const float bam = b_mu * a_mu;
    const float bas = b_s * a_s;
    const float c3  = b_s * (1.0f - a_s);

    // ---- stage y region into LDS: coalesced float4 loads, swizzled store ----
    for (int idx = t * 4; idx < REGION; idx += BLOCK * 4) {   // 17 iters exact
        int g = gbase + idx;
        float4 v;
        if (g >= 0) v = *(const float4*)(y + g);
        else        v = make_float4(0.f, 0.f, 0.f, 0.f);      // block 0 pre-pad
        int f = SWZ(idx);          // idx%4==0, idx%64<=60 -> 4 contiguous slots
        sy[f] = v.x; sy[f + 1] = v.y; sy[f + 2] = v.z; sy[f + 3] = v.w;
    }
    __syncthreads();

    // ---- initial state ----
    const int start = blk * OUTW + t * CHUNK;  // first emitted global index
    float mu, s2;
    int e, burn;
    if (start <= BURN) {                       // i0 <= 0: exact initial state
        mu   = *p_last_mu;
        s2   = *p_last_s2;                     // "last_sigma" is the variance
        e    = BURN;                           // LDS elem of global index 0
        burn = start;
    } else {                                   // stationary-point guess
        mu   = w_mu / fmaxf(1.0f - b_mu, 1e-6f);
        s2   = w_s  / fmaxf(1.0f - b_s,  1e-6f);
        e    = t * CHUNK;
        burn = BURN;
    }

#define STEP(yv) do {                                   \
        float r   = (yv) - mu;                          \
        float den = fmaf(r, r, nu * s2);                \
        float inv = __builtin_amdgcn_rcpf(den);         \
        float sr  = (c1 * s2) * inv * r;                \
        float m2  = fmaf(b_mu, mu, w_mu);               \
        float s2b = fmaf(c3, s2, w_s);                  \
        mu = fmaf(bam, sr, m2);                         \
        s2 = fmaf(bas, sr * r, s2b);                    \
    } while (0)

    // ---- burn-in: 4-deep rolling register prefetch from LDS ----
    float c0 = sy[SWZ(e)],     cc1 = sy[SWZ(e + 1)];
    float c2 = sy[SWZ(e + 2)], cc3 = sy[SWZ(e + 3)];
    for (int g = 0; g < burn; g += 4) {
        int ep = e + 4;
        float n0 = sy[SWZ(ep)],     n1 = sy[SWZ(ep + 1)];
        float n2 = sy[SWZ(ep + 2)], n3 = sy[SWZ(ep + 3)];
        STEP(c0); STEP(cc1); STEP(c2); STEP(cc3);
        c0 = n0; cc1 = n1; c2 = n2; cc3 = n3; e = ep;
    }

    // ---- emit: mu -> LDS (sm), sqrt(s2) -> registers ----
    float sreg[CHUNK];
    const int obase = t * CHUNK;
    #pragma unroll
    for (int g = 0; g < CHUNK; g += 4) {
        int ep = e + 4;
        float n0 = sy[SWZ(ep)],     n1 = sy[SWZ(ep + 1)];
        float n2 = sy[SWZ(ep + 2)], n3 = sy[SWZ(ep + 3)];
        STEP(c0);  sm[SWZ(obase + g + 0)] = mu; sreg[g + 0] = __builtin_amdgcn_sqrtf(s2);
        STEP(cc1); sm[SWZ(obase + g + 1)] = mu; sreg[g + 1] = __builtin_amdgcn_sqrtf(s2);
        STEP(c2);  sm[SWZ(obase + g + 2)] = mu; sreg[g + 2] = __builtin_amdgcn_sqrtf(s2);
        STEP(cc3); sm[SWZ(obase + g + 3)] = mu; sreg[g + 3] = __builtin_amdgcn_sqrtf(s2);
        c0 = n0; cc1 = n1; c2 = n2; cc3 = n3; e = ep;
    }
#undef STEP

    __syncthreads();                 // all sy reads done -> safe to reuse
    #pragma unroll
    for (int k = 0; k < CHUNK; ++k)
        sy[SWZ(obase + k)] = sreg[k];        // sigma into old y buffer
    __syncthreads();

    // ---- coalesced float4 stores of both outputs ----
    const int out_base = blk * OUTW;
    for (int it = 0; it < OUTW / (BLOCK * 4); ++it) {   // 16 iters
        int idx = t * 4 + it * BLOCK * 4;
        int f   = SWZ(idx);                             // 4 contiguous slots
        float4 v, w;
        v.x = sm[f]; v.y = sm[f + 1]; v.z = sm[f + 2]; v.w = sm[f + 3];
        w.x = sy[f]; w.y = sy[f + 1]; w.z = sy[f + 2]; w.w = sy[f + 3];
        *(float4*)(out + out_base + idx)     = v;
        *(float4*)(out + n + out_base + idx) = w;
    }
}

extern "C" void kernel_launch(void* const* d_in, const int* in_sizes, int n_in,
                              void* d_out, int out_size, void* d_ws, size_t ws_size,
                              hipStream_t stream) {
    const float* y = (const float*)d_in[0];
    const int n    = in_sizes[0];              // 4194304 = 512 * 8192
    const int grid = n / OUTW;                 // 512 blocks

    ar_gas_kernel<<<grid, BLOCK, 0, stream>>>(
        y,
        (const float*)d_in[1],  // last_mu
        (const float*)d_in[2],  // last_sigma (variance)
        (const float*)d_in[3],  // alpha_mu
        (const float*)d_in[4],  // alpha_sigma
        (const float*)d_in[5],  // beta_mu
        (const float*)d_in[6],  // beta_sigma
        (const float*)d_in[7],  // omega_mu
        (const float*)d_in[8],  // omega_sigma
        (const float*)d_in[9],  // nu
        (const float*)d_in[10], // norm_strength
        (float*)d_out, n);
}

// Round 4
// 103.766 us; speedup vs baseline: 2.6931x; 1.1065x over previous
//
#include <hip/hip_runtime.h>
#include <math.h>

// AR-GAS Student-t filter, K = 4194304 sequential steps.
// Chunked scan with burn-in (contractive map, avg per-step Jacobian ~0.94).
// R4: CHUNK 32 / BURN 256 (9x work, 2 chains/SIMD), ds_read_b128 via
// +4-per-32-float swizzle (conflict-free, immediate-offset addressing),
// in-place mu writeback (one 19.6 KB LDS buffer -> 4 blocks/CU), two-phase
// coalesced float4 copy-out. Issue-bound target ~80% VALUBusy.

#define CHUNK  32
#define BURN   256
#define BLOCK  128
#define OUTW   (BLOCK * CHUNK)          // 4096 outputs per block
#define REGION (OUTW + BURN)            // 4352 staged y elements
#define SWZ(e) ((e) + 4 * ((e) >> 5))   // +4 floats pad per 32 -> b128 conflict-free
#define SY_PAD 4896                     // > SWZ(REGION-1)+1 = 4892, mult of 4

__global__ __launch_bounds__(BLOCK, 2)
void ar_gas_kernel(const float* __restrict__ y,
                   const float* __restrict__ p_last_mu,
                   const float* __restrict__ p_last_s2,
                   const float* __restrict__ p_amu,
                   const float* __restrict__ p_as,
                   const float* __restrict__ p_bmu,
                   const float* __restrict__ p_bs,
                   const float* __restrict__ p_wmu,
                   const float* __restrict__ p_ws,
                   const float* __restrict__ p_nu,
                   const float* __restrict__ p_str,
                   float* __restrict__ out,
                   int n)
{
    __shared__ __align__(16) float sy[SY_PAD];
    const int t     = threadIdx.x;
    const int blk   = blockIdx.x;
    const int gbase = blk * OUTW - BURN;   // global index of LDS elem 0

    const float nu       = *p_nu;
    const float strength = *p_str;
    const float a_mu = (*p_amu) * strength;
    const float a_s  = (*p_as)  * strength;
    const float b_mu = *p_bmu;
    const float b_s  = *p_bs;
    const float w_mu = *p_wmu;
    const float w_s  = *p_ws;

    const float c1  = nu + 1.0f;           // scale = c1*s2 / (nu*s2 + r^2)
    const float bam = b_mu * a_mu;
    const float bas = b_s * a_s;
    const float c3  = b_s * (1.0f - a_s);

    // ---- stage y region: coalesced float4 global loads -> swizzled LDS ----
    #pragma unroll
    for (int it = 0; it < 9; ++it) {
        int idx = t * 4 + it * (BLOCK * 4);
        if (idx < REGION) {
            int g = gbase + idx;
            float4 v;
            if (g >= 0) v = *(const float4*)(y + g);
            else        v = make_float4(0.f, 0.f, 0.f, 0.f);  // block 0 pre-pad (never read)
            *(float4*)(sy + SWZ(idx)) = v;
        }
    }
    __syncthreads();

    // ---- initial state ----
    const int gstart = blk * OUTW + t * CHUNK;   // first emitted global index
    float mu, s2;
    int e0, burn;
    if (gstart < BURN) {                  // block 0, t<8: exact initial state
        mu   = *p_last_mu;
        s2   = *p_last_s2;                // "last_sigma" is the variance
        burn = gstart;                    // multiple of 32
        e0   = BURN;                      // LDS elem of global index 0
    } else {                              // stationary-point guess; burn erases it
        mu   = w_mu * __builtin_amdgcn_rcpf(fmaxf(1.0f - b_mu, 1e-12f));
        s2   = w_s  * __builtin_amdgcn_rcpf(fmaxf(1.0f - b_s,  1e-12f));
        burn = BURN;
        e0   = t * CHUNK;
    }

#define STEP(yv) do {                                   \
        float r   = (yv) - mu;                          \
        float den = fmaf(r, r, nu * s2);                \
        float inv = __builtin_amdgcn_rcpf(den);         \
        float sr  = (c1 * s2) * inv * r;                \
        float m2  = fmaf(b_mu, mu, w_mu);               \
        float s2b = fmaf(c3, s2, w_s);                  \
        mu = fmaf(bam, sr, m2);                         \
        s2 = fmaf(bas, sr * r, s2b);                    \
    } while (0)
#define STEP4(v) do { STEP((v).x); STEP((v).y); STEP((v).z); STEP((v).w); } while (0)
#define LDS4(fi) (*(const float4*)(sy + (fi)))

    // ---- burn-in: 32 steps/iter, b128 reads at immediate offsets ----
    int p = SWZ(e0);                       // padded float index (group-aligned)
    float4 c = LDS4(p);
    for (int g = 0; g < burn; g += 32) {
        float4 n1 = LDS4(p + 4);  STEP4(c);
        float4 n2 = LDS4(p + 8);  STEP4(n1);
        float4 n3 = LDS4(p + 12); STEP4(n2);
        float4 n4 = LDS4(p + 16); STEP4(n3);
        float4 n5 = LDS4(p + 20); STEP4(n4);
        float4 n6 = LDS4(p + 24); STEP4(n5);
        float4 n7 = LDS4(p + 28); STEP4(n6);
        p += 36;
        c = LDS4(p);              STEP4(n7);   // prefetch next group's first 4
    }

    // all burn reads (which cover other threads' emit slots) must finish
    // before any thread overwrites its emit slots with mu:
    __syncthreads();

    // ---- emit 32 steps: mu written in-place over consumed y, sigma -> regs ----
    float sg[CHUNK];
    float4 m;
#define EMIT4(v, j, off) do {                                          \
        STEP((v).x); m.x = mu; sg[(j)+0] = __builtin_amdgcn_sqrtf(s2); \
        STEP((v).y); m.y = mu; sg[(j)+1] = __builtin_amdgcn_sqrtf(s2); \
        STEP((v).z); m.z = mu; sg[(j)+2] = __builtin_amdgcn_sqrtf(s2); \
        STEP((v).w); m.w = mu; sg[(j)+3] = __builtin_amdgcn_sqrtf(s2); \
        *(float4*)(sy + p + (off)) = m;                                \
    } while (0)
    {
        float4 e1 = LDS4(p + 4);
        EMIT4(c, 0, 0);
        float4 e2 = LDS4(p + 8);  EMIT4(e1, 4, 4);
        float4 e3 = LDS4(p + 12); EMIT4(e2, 8, 8);
        float4 e4 = LDS4(p + 16); EMIT4(e3, 12, 12);
        float4 e5 = LDS4(p + 20); EMIT4(e4, 16, 16);
        float4 e6 = LDS4(p + 24); EMIT4(e5, 20, 20);
        float4 e7 = LDS4(p + 28); EMIT4(e6, 24, 24);
        EMIT4(e7, 28, 28);        // last group: no further prefetch
    }
#undef EMIT4
#undef LDS4
#undef STEP4
#undef STEP

    __syncthreads();

    // ---- coalesced copy-out: mu ----
    const int obase = blk * OUTW;
    #pragma unroll
    for (int it = 0; it < OUTW / (BLOCK * 4); ++it) {    // 8 iters
        int idx = t * 4 + it * (BLOCK * 4);
        float4 v = *(const float4*)(sy + SWZ(idx + BURN));
        *(float4*)(out + obase + idx) = v;
    }
    __syncthreads();

    // ---- sigma regs -> LDS (same slots), then coalesced copy-out ----
    {
        int q = SWZ(t * CHUNK + BURN);     // group-aligned, 32 floats in-group
        *(float4*)(sy + q +  0) = make_float4(sg[ 0], sg[ 1], sg[ 2], sg[ 3]);
        *(float4*)(sy + q +  4) = make_float4(sg[ 4], sg[ 5], sg[ 6], sg[ 7]);
        *(float4*)(sy + q +  8) = make_float4(sg[ 8], sg[ 9], sg[10], sg[11]);
        *(float4*)(sy + q + 12) = make_float4(sg[12], sg[13], sg[14], sg[15]);
        *(float4*)(sy + q + 16) = make_float4(sg[16], sg[17], sg[18], sg[19]);
        *(float4*)(sy + q + 20) = make_float4(sg[20], sg[21], sg[22], sg[23]);
        *(float4*)(sy + q + 24) = make_float4(sg[24], sg[25], sg[26], sg[27]);
        *(float4*)(sy + q + 28) = make_float4(sg[28], sg[29], sg[30], sg[31]);
    }
    __syncthreads();
    #pragma unroll
    for (int it = 0; it < OUTW / (BLOCK * 4); ++it) {    // 8 iters
        int idx = t * 4 + it * (BLOCK * 4);
        float4 v = *(const float4*)(sy + SWZ(idx + BURN));
        *(float4*)(out + n + obase + idx) = v;
    }
}

extern "C" void kernel_launch(void* const* d_in, const int* in_sizes, int n_in,
                              void* d_out, int out_size, void* d_ws, size_t ws_size,
                              hipStream_t stream) {
    const float* y = (const float*)d_in[0];
    const int n    = in_sizes[0];              // 4194304 = 1024 * 4096
    const int grid = n / OUTW;                 // 1024 blocks

    ar_gas_kernel<<<grid, BLOCK, 0, stream>>>(
        y,
        (const float*)d_in[1],  // last_mu
        (const float*)d_in[2],  // last_sigma (variance)
        (const float*)d_in[3],  // alpha_mu
        (const float*)d_in[4],  // alpha_sigma
        (const float*)d_in[5],  // beta_mu
        (const float*)d_in[6],  // beta_sigma
        (const float*)d_in[7],  // omega_mu
        (const float*)d_in[8],  // omega_sigma
        (const float*)d_in[9],  // nu
        (const float*)d_in[10], // norm_strength
        (float*)d_out, n);
}